// Round 2
// baseline (537.164 us; speedup 1.0000x reference)
//
#include <hip/hip_runtime.h>

// ============================================================================
// CG tensor product + complex weight contraction, fused per batch element.
// Reference: LMAX=5, TAU_PRE=16, TAU=16, B=256.
// Inputs (setup_inputs dict order): f0,w0,f1,w1,...,f5,w5
//   f_l: [256,16,2l+1,2] fp32; w_l: [16,NUMCOLS[l],2] fp32
// Output: concat of out_l [256,16,2l+1,2], l=0..5 (fp32, 294912 elements)
// ============================================================================

constexpr int LMAXC = 5;

constexpr int imin_(int a, int b) { return a < b ? a : b; }

// Global triple enumeration (l1 asc, l2<=l1 asc, l asc) -> coefficient offset
constexpr int coef_off_of(int L1, int L2, int L) {
    int off = 0;
    for (int l1 = 0; l1 <= LMAXC; ++l1)
        for (int l2 = 0; l2 <= l1; ++l2) {
            const int hi = imin_(l1 + l2, LMAXC);
            for (int l = l1 - l2; l <= hi; ++l) {
                if (l1 == L1 && l2 == L2 && l == L) return off;
                off += (2 * l1 + 1) * (2 * l2 + 1);
            }
        }
    return -1;
}

constexpr int count_triples() {
    int n = 0;
    for (int l1 = 0; l1 <= LMAXC; ++l1)
        for (int l2 = 0; l2 <= l1; ++l2) {
            const int hi = imin_(l1 + l2, LMAXC);
            for (int l = l1 - l2; l <= hi; ++l) ++n;
        }
    return n;
}
constexpr int NTRI = count_triples();  // 69

constexpr int total_coef() {
    int off = 0;
    for (int l1 = 0; l1 <= LMAXC; ++l1)
        for (int l2 = 0; l2 <= l1; ++l2) {
            const int hi = imin_(l1 + l2, LMAXC);
            for (int l = l1 - l2; l <= hi; ++l) off += (2 * l1 + 1) * (2 * l2 + 1);
        }
    return off;
}
constexpr int TOTAL_COEF = total_coef();  // 3587

// Per-l tables
constexpr int FOFF_[6]    = {0, 32, 128, 288, 512, 800};          // f staging offsets (floats)
constexpr int OUTOFF_[6]  = {0, 8192, 32768, 73728, 131072, 204800};
constexpr int NUMCOLS_[6] = {1536, 2560, 3328, 3584, 3584, 3072};
constexpr int FR = 514;  // frag LDS row stride in floats (256*2 + 2 pad)

// ============================================================================
// Init kernel: compute CG coefficients (Racah formula, double) into d_ws.
// Runs every launch (d_ws is re-poisoned before each timed call).
// ============================================================================
__device__ double dfact(int n) {
    double r = 1.0;
    for (int i = 2; i <= n; ++i) r *= (double)i;
    return r;
}

__device__ double cg_coeff_d(int l1, int l2, int l, int m1, int m2, int m) {
    double pref = (2.0 * l + 1.0) * dfact(l + l1 - l2) * dfact(l - l1 + l2) *
                  dfact(l1 + l2 - l) / dfact(l1 + l2 + l + 1);
    pref *= dfact(l + m) * dfact(l - m) * dfact(l1 - m1) * dfact(l1 + m1) *
            dfact(l2 - m2) * dfact(l2 + m2);
    pref = sqrt(pref);
    int kmin = 0;
    if (l2 - l - m1 > kmin) kmin = l2 - l - m1;
    if (l1 + m2 - l > kmin) kmin = l1 + m2 - l;
    int kmax = l1 + l2 - l;
    if (l1 - m1 < kmax) kmax = l1 - m1;
    if (l2 + m2 < kmax) kmax = l2 + m2;
    double s = 0.0;
    for (int k = kmin; k <= kmax; ++k) {
        const double d = dfact(k) * dfact(l1 + l2 - l - k) * dfact(l1 - m1 - k) *
                         dfact(l2 + m2 - k) * dfact(l - l2 + m1 + k) * dfact(l - l1 - m2 + k);
        s += ((k & 1) ? -1.0 : 1.0) / d;
    }
    return pref * s;
}

__global__ void cg_init_kernel(float* __restrict__ coef) {
    const int target = blockIdx.x;
    int off = 0, n = 0;
    int L1 = -1, L2 = 0, LL = 0;
    for (int l1 = 0; l1 <= 5 && L1 < 0; ++l1) {
        for (int l2 = 0; l2 <= l1 && L1 < 0; ++l2) {
            const int hi = (l1 + l2 < 5) ? (l1 + l2) : 5;
            for (int l = l1 - l2; l <= hi; ++l) {
                if (n == target) { L1 = l1; L2 = l2; LL = l; break; }
                off += (2 * l1 + 1) * (2 * l2 + 1);
                ++n;
            }
        }
    }
    if (L1 < 0) return;
    const int n1 = 2 * L1 + 1, n2 = 2 * L2 + 1, sz = n1 * n2;
    for (int idx = threadIdx.x; idx < sz; idx += blockDim.x) {
        const int m1 = idx / n2 - L1;
        const int m2 = idx % n2 - L2;
        const int mm = m1 + m2;
        double v = 0.0;
        if (mm >= -LL && mm <= LL) v = cg_coeff_d(L1, L2, LL, m1, m2, mm);
        coef[off + idx] = (float)v;
    }
}

// ============================================================================
// Main fused kernel
// ============================================================================
template <int L, int L1, int L2>
__device__ __forceinline__ void do_triple(
    const float* __restrict__ coef, const float* __restrict__ wl,
    const float* __restrict__ sh_f, float* __restrict__ sh_frag,
    const int tid, const int colbase, float& accR, float& accI)
{
    constexpr int CO = coef_off_of(L1, L2, L);
    constexpr int N1 = 2 * L1 + 1, N2 = 2 * L2 + 1, NK = 2 * L + 1;
    constexpr int SH = L1 + L2 - L;

    // ---- phase 1: frag[k] for this thread's (i,j) channel pair ----
    {
        const int i = tid >> 4, j = tid & 15;
        const float* f1 = sh_f + FOFF_[L1] + i * (2 * N1);
        const float* f2 = sh_f + FOFF_[L2] + j * (2 * N2);
        float f1r[N1], f1i[N1], f2r[N2], f2i[N2];
#pragma unroll
        for (int m = 0; m < N1; ++m) { float2 v = *(const float2*)(f1 + 2 * m); f1r[m] = v.x; f1i[m] = v.y; }
#pragma unroll
        for (int n = 0; n < N2; ++n) { float2 v = *(const float2*)(f2 + 2 * n); f2r[n] = v.x; f2i[n] = v.y; }
#pragma unroll
        for (int k = 0; k < NK; ++k) {
            const int kk = k + SH;
            float fr = 0.f, fi = 0.f;
#pragma unroll
            for (int m1 = 0; m1 < N1; ++m1) {
                const int m2 = kk - m1;
                if (m2 >= 0 && m2 < N2) {  // compile-time after unroll
                    const float c = coef[CO + m1 * N2 + m2];
                    fr += c * (f1r[m1] * f2r[m2] - f1i[m1] * f2i[m2]);
                    fi += c * (f1r[m1] * f2i[m2] + f1i[m1] * f2r[m2]);
                }
            }
            *(float2*)(sh_frag + k * FR + 2 * tid) = make_float2(fr, fi);
        }
    }
    __syncthreads();

    // ---- phase 2: out[t,k] += sum_ij w[t, colbase+ij] * frag[ij,k] ----
    if (tid < 16 * NK) {
        const int t = tid & 15, k = tid >> 4;
        const float* __restrict__ wp = wl + ((size_t)t * NUMCOLS_[L] + colbase) * 2;
        const float* __restrict__ fg = sh_frag + k * FR;
        float sR = 0.f, sI = 0.f;
#pragma unroll 8
        for (int ij = 0; ij < 256; ++ij) {
            const float2 wv = *(const float2*)(wp + 2 * ij);
            const float2 fv = *(const float2*)(fg + 2 * ij);
            sR += wv.x * fv.x - wv.y * fv.y;
            sI += wv.x * fv.y + wv.y * fv.x;
        }
        accR += sR; accI += sI;
    }
    __syncthreads();
}

template <int L>
__device__ void run_l(const float* const* fs, const float* __restrict__ wl,
                      const float* __restrict__ coef, float* __restrict__ out,
                      float* sh_f, float* sh_frag)
{
    const int b = blockIdx.x;
    const int tid = threadIdx.x;

    // stage all f_l[b] into LDS (1152 floats)
#pragma unroll
    for (int l = 0; l < 6; ++l) {
        const int cnt = 32 * (2 * l + 1);
        const float* src = fs[l] + (size_t)b * cnt;
        for (int idx = tid; idx < cnt; idx += 256) sh_f[FOFF_[l] + idx] = src[idx];
    }
    __syncthreads();

    float accR = 0.f, accI = 0.f;
    int cb = 0;
#define T_(A, B) do_triple<L, A, B>(coef, wl, sh_f, sh_frag, tid, cb, accR, accI); cb += 256;
    if constexpr (L == 0) { T_(0,0) T_(1,1) T_(2,2) T_(3,3) T_(4,4) T_(5,5) }
    if constexpr (L == 1) { T_(1,0) T_(1,1) T_(2,1) T_(2,2) T_(3,2) T_(3,3) T_(4,3) T_(4,4) T_(5,4) T_(5,5) }
    if constexpr (L == 2) { T_(1,1) T_(2,0) T_(2,1) T_(2,2) T_(3,1) T_(3,2) T_(3,3) T_(4,2) T_(4,3) T_(4,4) T_(5,3) T_(5,4) T_(5,5) }
    if constexpr (L == 3) { T_(2,1) T_(2,2) T_(3,0) T_(3,1) T_(3,2) T_(3,3) T_(4,1) T_(4,2) T_(4,3) T_(4,4) T_(5,2) T_(5,3) T_(5,4) T_(5,5) }
    if constexpr (L == 4) { T_(2,2) T_(3,1) T_(3,2) T_(3,3) T_(4,0) T_(4,1) T_(4,2) T_(4,3) T_(4,4) T_(5,1) T_(5,2) T_(5,3) T_(5,4) T_(5,5) }
    if constexpr (L == 5) { T_(3,2) T_(3,3) T_(4,1) T_(4,2) T_(4,3) T_(4,4) T_(5,0) T_(5,1) T_(5,2) T_(5,3) T_(5,4) T_(5,5) }
#undef T_

    constexpr int NK = 2 * L + 1;
    if (tid < 16 * NK) {
        const int t = tid & 15, k = tid >> 4;
        const size_t o = (size_t)OUTOFF_[L] + ((size_t)(b * 16 + t) * NK + k) * 2;
        out[o] = accR;
        out[o + 1] = accI;
    }
}

__global__ __launch_bounds__(256)
void update_kernel(const float* __restrict__ f0, const float* __restrict__ f1,
                   const float* __restrict__ f2, const float* __restrict__ f3,
                   const float* __restrict__ f4, const float* __restrict__ f5,
                   const float* __restrict__ w0, const float* __restrict__ w1,
                   const float* __restrict__ w2, const float* __restrict__ w3,
                   const float* __restrict__ w4, const float* __restrict__ w5,
                   const float* __restrict__ coef, float* __restrict__ out)
{
    __shared__ float sh_f[1152];
    __shared__ float sh_frag[11 * FR];
    const float* fs[6] = {f0, f1, f2, f3, f4, f5};
    switch (blockIdx.y) {
        case 0: run_l<0>(fs, w0, coef, out, sh_f, sh_frag); break;
        case 1: run_l<1>(fs, w1, coef, out, sh_f, sh_frag); break;
        case 2: run_l<2>(fs, w2, coef, out, sh_f, sh_frag); break;
        case 3: run_l<3>(fs, w3, coef, out, sh_f, sh_frag); break;
        case 4: run_l<4>(fs, w4, coef, out, sh_f, sh_frag); break;
        default: run_l<5>(fs, w5, coef, out, sh_f, sh_frag); break;
    }
}

// ============================================================================
extern "C" void kernel_launch(void* const* d_in, const int* in_sizes, int n_in,
                              void* d_out, int out_size, void* d_ws, size_t ws_size,
                              hipStream_t stream)
{
    const float* f[6];
    const float* w[6];
    for (int l = 0; l < 6; ++l) {
        f[l] = (const float*)d_in[2 * l];      // f0,w0,f1,w1,... dict order
        w[l] = (const float*)d_in[2 * l + 1];
    }
    float* coef = (float*)d_ws;  // TOTAL_COEF floats (14.3 KB)

    cg_init_kernel<<<dim3(NTRI), dim3(64), 0, stream>>>(coef);

    update_kernel<<<dim3(256, 6), dim3(256), 0, stream>>>(
        f[0], f[1], f[2], f[3], f[4], f[5],
        w[0], w[1], w[2], w[3], w[4], w[5],
        coef, (float*)d_out);
}

// Round 3
// 271.934 us; speedup vs baseline: 1.9753x; 1.9753x over previous
//
#include <hip/hip_runtime.h>
#include <utility>

// ============================================================================
// CG tensor product + complex weight contraction, fused per batch element.
// LMAX=5, TAU_PRE=16, TAU=16, B=256.
// Inputs (dict order): f0,w0,f1,w1,...,f5,w5
//   f_l: [256,16,2l+1,2] fp32; w_l: [16,NUMCOLS[l],2] fp32
// Output: concat of out_l [256,16,2l+1,2], l=0..5 (fp32, 294912 elements)
//
// Block = (b, L): 256 threads. Per triple (l1,l2,L):
//   phase1: thread (i=tid>>4, j=tid&15) computes frag[k][ij=tid] (CG contract)
//   phase2: thread (t=tid>>4, g=tid&15) accumulates acc[k] over ij≡g (mod 16)
// frag double-buffered in LDS -> 1 barrier per triple. Final shfl_xor reduce
// over g once per block.
// ============================================================================

constexpr int LMAXC = 5;
constexpr int imin_(int a, int b) { return a < b ? a : b; }

constexpr int coef_off_of(int L1, int L2, int L) {
    int off = 0;
    for (int l1 = 0; l1 <= LMAXC; ++l1)
        for (int l2 = 0; l2 <= l1; ++l2) {
            const int hi = imin_(l1 + l2, LMAXC);
            for (int l = l1 - l2; l <= hi; ++l) {
                if (l1 == L1 && l2 == L2 && l == L) return off;
                off += (2 * l1 + 1) * (2 * l2 + 1);
            }
        }
    return -1;
}

constexpr int NTRI = 69;

// Per-l tables
constexpr int FOFF_[6]    = {0, 32, 128, 288, 512, 800};
constexpr int OUTOFF_[6]  = {0, 8192, 32768, 73728, 131072, 204800};
constexpr int NUMCOLS_[6] = {1536, 2560, 3328, 3584, 3584, 3072};
constexpr int FR = 514;  // frag row stride (256*2 + 2 pad)

// Triple lists per output L, reference enumeration order (l1 asc, l2<=l1 asc)
constexpr int TRI_N[6] = {6, 10, 13, 14, 14, 12};
constexpr int TRI_L1[6][14] = {
    {0,1,2,3,4,5, 0,0,0,0,0,0,0,0},
    {1,1,2,2,3,3,4,4,5,5, 0,0,0,0},
    {1,2,2,2,3,3,3,4,4,4,5,5,5, 0},
    {2,2,3,3,3,3,4,4,4,4,5,5,5,5},
    {2,3,3,3,4,4,4,4,4,5,5,5,5,5},
    {3,3,4,4,4,4,5,5,5,5,5,5, 0,0}};
constexpr int TRI_L2[6][14] = {
    {0,1,2,3,4,5, 0,0,0,0,0,0,0,0},
    {0,1,1,2,2,3,3,4,4,5, 0,0,0,0},
    {1,0,1,2,1,2,3,2,3,4,3,4,5, 0},
    {1,2,0,1,2,3,1,2,3,4,2,3,4,5},
    {2,1,2,3,0,1,2,3,4,1,2,3,4,5},
    {2,3,1,2,3,4,0,1,2,3,4,5, 0,0}};

// ============================================================================
// Init kernel: CG coefficients (Racah, double) into d_ws (re-poisoned per call)
// ============================================================================
__device__ double dfact(int n) {
    double r = 1.0;
    for (int i = 2; i <= n; ++i) r *= (double)i;
    return r;
}

__device__ double cg_coeff_d(int l1, int l2, int l, int m1, int m2, int m) {
    double pref = (2.0 * l + 1.0) * dfact(l + l1 - l2) * dfact(l - l1 + l2) *
                  dfact(l1 + l2 - l) / dfact(l1 + l2 + l + 1);
    pref *= dfact(l + m) * dfact(l - m) * dfact(l1 - m1) * dfact(l1 + m1) *
            dfact(l2 - m2) * dfact(l2 + m2);
    pref = sqrt(pref);
    int kmin = 0;
    if (l2 - l - m1 > kmin) kmin = l2 - l - m1;
    if (l1 + m2 - l > kmin) kmin = l1 + m2 - l;
    int kmax = l1 + l2 - l;
    if (l1 - m1 < kmax) kmax = l1 - m1;
    if (l2 + m2 < kmax) kmax = l2 + m2;
    double s = 0.0;
    for (int k = kmin; k <= kmax; ++k) {
        const double d = dfact(k) * dfact(l1 + l2 - l - k) * dfact(l1 - m1 - k) *
                         dfact(l2 + m2 - k) * dfact(l - l2 + m1 + k) * dfact(l - l1 - m2 + k);
        s += ((k & 1) ? -1.0 : 1.0) / d;
    }
    return pref * s;
}

__global__ void cg_init_kernel(float* __restrict__ coef) {
    const int target = blockIdx.x;
    int off = 0, n = 0;
    int L1 = -1, L2 = 0, LL = 0;
    for (int l1 = 0; l1 <= 5 && L1 < 0; ++l1) {
        for (int l2 = 0; l2 <= l1 && L1 < 0; ++l2) {
            const int hi = (l1 + l2 < 5) ? (l1 + l2) : 5;
            for (int l = l1 - l2; l <= hi; ++l) {
                if (n == target) { L1 = l1; L2 = l2; LL = l; break; }
                off += (2 * l1 + 1) * (2 * l2 + 1);
                ++n;
            }
        }
    }
    if (L1 < 0) return;
    const int n1 = 2 * L1 + 1, n2 = 2 * L2 + 1, sz = n1 * n2;
    for (int idx = threadIdx.x; idx < sz; idx += blockDim.x) {
        const int m1 = idx / n2 - L1;
        const int m2 = idx % n2 - L2;
        const int mm = m1 + m2;
        double v = 0.0;
        if (mm >= -LL && mm <= LL) v = cg_coeff_d(L1, L2, LL, m1, m2, mm);
        coef[off + idx] = (float)v;
    }
}

// ============================================================================
// Main fused kernel
// ============================================================================
template <int L, int L1, int L2>
__device__ __forceinline__ void do_phase1(
    const float* __restrict__ coef, const float* __restrict__ sh_f,
    float* __restrict__ frag, const int tid)
{
    constexpr int CO = coef_off_of(L1, L2, L);
    constexpr int N1 = 2 * L1 + 1, N2 = 2 * L2 + 1, NK = 2 * L + 1;
    constexpr int SH = L1 + L2 - L;

    const int i = tid >> 4, j = tid & 15;
    const float* f1 = sh_f + FOFF_[L1] + i * (2 * N1);
    const float* f2 = sh_f + FOFF_[L2] + j * (2 * N2);
    float f1r[N1], f1i[N1], f2r[N2], f2i[N2];
#pragma unroll
    for (int m = 0; m < N1; ++m) { float2 v = *(const float2*)(f1 + 2 * m); f1r[m] = v.x; f1i[m] = v.y; }
#pragma unroll
    for (int n = 0; n < N2; ++n) { float2 v = *(const float2*)(f2 + 2 * n); f2r[n] = v.x; f2i[n] = v.y; }
#pragma unroll
    for (int k = 0; k < NK; ++k) {
        const int kk = k + SH;
        float fr = 0.f, fi = 0.f;
#pragma unroll
        for (int m1 = 0; m1 < N1; ++m1) {
            const int m2 = kk - m1;
            if (m2 >= 0 && m2 < N2) {  // compile-time after unroll
                const float c = coef[CO + m1 * N2 + m2];
                fr += c * (f1r[m1] * f2r[m2] - f1i[m1] * f2i[m2]);
                fi += c * (f1r[m1] * f2i[m2] + f1i[m1] * f2r[m2]);
            }
        }
        *(float2*)(frag + k * FR + 2 * tid) = make_float2(fr, fi);
    }
}

template <int L>
__device__ __forceinline__ void do_phase2(
    const float* __restrict__ frag, const float* __restrict__ wl,
    const int colbase, const int t, const int g, float* __restrict__ acc)
{
    constexpr int NK = 2 * L + 1;
    const float* __restrict__ wp = wl + ((size_t)t * NUMCOLS_[L] + colbase + g) * 2;
#pragma unroll 4
    for (int i = 0; i < 16; ++i) {
        const float2 wv = *(const float2*)(wp + 32 * i);
        const int ij = g + 16 * i;
#pragma unroll
        for (int k = 0; k < NK; ++k) {
            const float2 fv = *(const float2*)(frag + k * FR + 2 * ij);
            acc[2 * k]     += wv.x * fv.x - wv.y * fv.y;
            acc[2 * k + 1] += wv.x * fv.y + wv.y * fv.x;
        }
    }
}

template <int L, int IDX>
__device__ __forceinline__ void step(
    const float* __restrict__ coef, const float* __restrict__ wl,
    const float* __restrict__ sh_f, float* __restrict__ buf0, float* __restrict__ buf1,
    const int tid, const int t, const int g, float* __restrict__ acc)
{
    constexpr int NT = TRI_N[L];
    if constexpr (IDX > 0) {
        do_phase2<L>(((IDX - 1) & 1) ? buf1 : buf0, wl, (IDX - 1) * 256, t, g, acc);
    }
    if constexpr (IDX < NT) {
        constexpr int L1 = TRI_L1[L][IDX];
        constexpr int L2 = TRI_L2[L][IDX];
        do_phase1<L, L1, L2>(coef, sh_f, (IDX & 1) ? buf1 : buf0, tid);
        __syncthreads();
    }
}

template <int L, int... Is>
__device__ __forceinline__ void run_steps(
    std::integer_sequence<int, Is...>,
    const float* coef, const float* wl, const float* sh_f,
    float* buf0, float* buf1, int tid, int t, int g, float* acc)
{
    (step<L, Is>(coef, wl, sh_f, buf0, buf1, tid, t, g, acc), ...);
}

template <int L>
__device__ void run_l(const float* const* fs, const float* __restrict__ wl,
                      const float* __restrict__ coef, float* __restrict__ out,
                      float* sh_f, float* buf0, float* buf1)
{
    const int b = blockIdx.x;
    const int tid = threadIdx.x;
    const int t = tid >> 4, g = tid & 15;

    // stage all f_l[b] into LDS (1152 floats)
#pragma unroll
    for (int l = 0; l < 6; ++l) {
        const int cnt = 32 * (2 * l + 1);
        const float* src = fs[l] + (size_t)b * cnt;
        for (int idx = tid; idx < cnt; idx += 256) sh_f[FOFF_[l] + idx] = src[idx];
    }
    __syncthreads();

    constexpr int NK = 2 * L + 1;
    float acc[2 * NK];
#pragma unroll
    for (int k = 0; k < 2 * NK; ++k) acc[k] = 0.f;

    run_steps<L>(std::make_integer_sequence<int, TRI_N[L] + 1>{},
                 coef, wl, sh_f, buf0, buf1, tid, t, g, acc);

    // reduce over g (low 4 lane bits) via xor-shuffle
#pragma unroll
    for (int k = 0; k < 2 * NK; ++k) {
        float v = acc[k];
        v += __shfl_xor(v, 1, 64);
        v += __shfl_xor(v, 2, 64);
        v += __shfl_xor(v, 4, 64);
        v += __shfl_xor(v, 8, 64);
        acc[k] = v;
    }
    if (g == 0) {
        float* op = out + OUTOFF_[L] + ((size_t)(b * 16 + t) * NK) * 2;
#pragma unroll
        for (int k = 0; k < NK; ++k)
            *(float2*)(op + 2 * k) = make_float2(acc[2 * k], acc[2 * k + 1]);
    }
}

__global__ __launch_bounds__(256)
void update_kernel(const float* __restrict__ f0, const float* __restrict__ f1,
                   const float* __restrict__ f2, const float* __restrict__ f3,
                   const float* __restrict__ f4, const float* __restrict__ f5,
                   const float* __restrict__ w0, const float* __restrict__ w1,
                   const float* __restrict__ w2, const float* __restrict__ w3,
                   const float* __restrict__ w4, const float* __restrict__ w5,
                   const float* __restrict__ coef, float* __restrict__ out)
{
    __shared__ float sh_f[1152];
    __shared__ float sh_buf0[11 * FR];
    __shared__ float sh_buf1[11 * FR];
    const float* fs[6] = {f0, f1, f2, f3, f4, f5};
    switch (blockIdx.y) {
        case 0: run_l<0>(fs, w0, coef, out, sh_f, sh_buf0, sh_buf1); break;
        case 1: run_l<1>(fs, w1, coef, out, sh_f, sh_buf0, sh_buf1); break;
        case 2: run_l<2>(fs, w2, coef, out, sh_f, sh_buf0, sh_buf1); break;
        case 3: run_l<3>(fs, w3, coef, out, sh_f, sh_buf0, sh_buf1); break;
        case 4: run_l<4>(fs, w4, coef, out, sh_f, sh_buf0, sh_buf1); break;
        default: run_l<5>(fs, w5, coef, out, sh_f, sh_buf0, sh_buf1); break;
    }
}

// ============================================================================
extern "C" void kernel_launch(void* const* d_in, const int* in_sizes, int n_in,
                              void* d_out, int out_size, void* d_ws, size_t ws_size,
                              hipStream_t stream)
{
    const float* f[6];
    const float* w[6];
    for (int l = 0; l < 6; ++l) {
        f[l] = (const float*)d_in[2 * l];      // f0,w0,f1,w1,... dict order
        w[l] = (const float*)d_in[2 * l + 1];
    }
    float* coef = (float*)d_ws;  // 3587 floats (14.3 KB)

    cg_init_kernel<<<dim3(NTRI), dim3(64), 0, stream>>>(coef);

    update_kernel<<<dim3(256, 6), dim3(256), 0, stream>>>(
        f[0], f[1], f[2], f[3], f[4], f[5],
        w[0], w[1], w[2], w[3], w[4], w[5],
        coef, (float*)d_out);
}

// Round 4
// 149.236 us; speedup vs baseline: 3.5994x; 1.8222x over previous
//
#include <hip/hip_runtime.h>
#include <hip/hip_bf16.h>
#include <utility>

// ============================================================================
// CG tensor product + complex weight contraction, fused per batch element.
// LMAX=5, TAU_PRE=16, TAU=16, B=256.
// Inputs (dict order): f0,w0,...,f5,w5. f_l:[256,16,2l+1,2] f32; w_l:[16,C_l,2] f32
// Output: concat of out_l [256,16,2l+1,2] f32 (294912 elems).
//
// Block=(b,L), 256 thr (4 waves).
//  phase1 (VALU): thread ij=(i=tid>>4, j=tid&15) computes frag[k] complex via
//    CG contract (coeffs are compile-time constants), writes bf16 into LDS
//    tile fragT[col][ij]  (col<NK: real, col=NK+k: imag), XOR-swizzled.
//  phase2 (MFMA): GEMM P[32, 2NK] += A2[32, 256]·fragT[256, 2NK] per triple,
//    A2 rows 0-15 = wR, 16-31 = wI (bf16-converted on the fly from f32 w).
//    K split across 4 waves (64 each), P in AGPRs across all triples.
//  epilogue: P partials -> LDS, cross-wave sum + complex combine, store.
// ============================================================================

using f32x4  = __attribute__((ext_vector_type(4))) float;
using bf16x8 = __attribute__((ext_vector_type(8))) short;

constexpr int OUTOFF_[6]  = {0, 8192, 32768, 73728, 131072, 204800};
constexpr int NUMCOLS_[6] = {1536, 2560, 3328, 3584, 3584, 3072};
constexpr int FOFF_[6]    = {0, 32, 128, 288, 512, 800};

constexpr int TRI_N[6] = {6, 10, 13, 14, 14, 12};
constexpr int TRI_L1[6][14] = {
    {0,1,2,3,4,5, 0,0,0,0,0,0,0,0},
    {1,1,2,2,3,3,4,4,5,5, 0,0,0,0},
    {1,2,2,2,3,3,3,4,4,4,5,5,5, 0},
    {2,2,3,3,3,3,4,4,4,4,5,5,5,5},
    {2,3,3,3,4,4,4,4,4,5,5,5,5,5},
    {3,3,4,4,4,4,5,5,5,5,5,5, 0,0}};
constexpr int TRI_L2[6][14] = {
    {0,1,2,3,4,5, 0,0,0,0,0,0,0,0},
    {0,1,1,2,2,3,3,4,4,5, 0,0,0,0},
    {1,0,1,2,1,2,3,2,3,4,3,4,5, 0},
    {1,2,0,1,2,3,1,2,3,4,2,3,4,5},
    {2,1,2,3,0,1,2,3,4,1,2,3,4,5},
    {2,3,1,2,3,4,0,1,2,3,4,5, 0,0}};

// ---------------- compile-time Clebsch-Gordan ----------------
constexpr double cfact(int n) { double r = 1.0; for (int i = 2; i <= n; ++i) r *= (double)i; return r; }

constexpr double csqrt(double x) {
    if (x <= 0.0) return 0.0;
    double g = x < 1.0 ? 1.0 : x;
    for (int i = 0; i < 200; ++i) {
        double n = 0.5 * (g + x / g);
        if (n == g) break;
        g = n;
    }
    return g;
}

constexpr double cg_c(int l1, int l2, int l, int m1, int m2, int m) {
    double pref = (2.0 * l + 1.0) * cfact(l + l1 - l2) * cfact(l - l1 + l2) *
                  cfact(l1 + l2 - l) / cfact(l1 + l2 + l + 1);
    pref *= cfact(l + m) * cfact(l - m) * cfact(l1 - m1) * cfact(l1 + m1) *
            cfact(l2 - m2) * cfact(l2 + m2);
    pref = csqrt(pref);
    int kmin = 0;
    if (l2 - l - m1 > kmin) kmin = l2 - l - m1;
    if (l1 + m2 - l > kmin) kmin = l1 + m2 - l;
    int kmax = l1 + l2 - l;
    if (l1 - m1 < kmax) kmax = l1 - m1;
    if (l2 + m2 < kmax) kmax = l2 + m2;
    double s = 0.0;
    for (int k = kmin; k <= kmax; ++k) {
        double d = cfact(k) * cfact(l1 + l2 - l - k) * cfact(l1 - m1 - k) *
                   cfact(l2 + m2 - k) * cfact(l - l2 + m1 + k) * cfact(l - l1 - m2 + k);
        s += ((k & 1) ? -1.0 : 1.0) / d;
    }
    return pref * s;
}

template <int L1, int L2, int L>
struct CGTab {
    static constexpr int N1 = 2 * L1 + 1, N2 = 2 * L2 + 1;
    struct T { float v[N1 * N2]; };
    static constexpr T build() {
        T t{};
        for (int m1 = -L1; m1 <= L1; ++m1)
            for (int m2 = -L2; m2 <= L2; ++m2) {
                int m = m1 + m2;
                double v = 0.0;
                if (m >= -L && m <= L) v = cg_c(L1, L2, L, m1, m2, m);
                t.v[(m1 + L1) * N2 + (m2 + L2)] = (float)v;
            }
        return t;
    }
    static constexpr T TAB = build();
};

// ---------------- helpers ----------------
__device__ __forceinline__ short f2bf(float f) {
    __hip_bfloat16 h = __float2bfloat16(f);
    return *reinterpret_cast<short*>(&h);
}

// ---------------- phase 1: CG contract -> swizzled bf16 LDS tile ----------------
template <int L, int L1, int L2>
__device__ __forceinline__ void do_phase1(const float* __restrict__ sh_f,
                                          char* __restrict__ fragT, const int tid)
{
    constexpr int N1 = 2 * L1 + 1, N2 = 2 * L2 + 1, NK = 2 * L + 1, SH = L1 + L2 - L;
    const int i = tid >> 4, j = tid & 15;
    const float* f1 = sh_f + FOFF_[L1] + i * (2 * N1);
    const float* f2 = sh_f + FOFF_[L2] + j * (2 * N2);
    float f1r[N1], f1i[N1], f2r[N2], f2i[N2];
#pragma unroll
    for (int m = 0; m < N1; ++m) { float2 v = *(const float2*)(f1 + 2 * m); f1r[m] = v.x; f1i[m] = v.y; }
#pragma unroll
    for (int n = 0; n < N2; ++n) { float2 v = *(const float2*)(f2 + 2 * n); f2r[n] = v.x; f2i[n] = v.y; }

    const int ij2 = tid * 2;
#pragma unroll
    for (int k = 0; k < NK; ++k) {
        const int kk = k + SH;
        float fr = 0.f, fi = 0.f;
#pragma unroll
        for (int m1 = 0; m1 < N1; ++m1) {
            const int m2 = kk - m1;
            if (m2 >= 0 && m2 < N2) {  // compile-time after unroll
                const float c = CGTab<L1, L2, L>::TAB.v[m1 * N2 + m2];
                if (c != 0.f) {        // folded constant -> zero terms DCE'd
                    fr += c * (f1r[m1] * f2r[m2] - f1i[m1] * f2i[m2]);
                    fi += c * (f1r[m1] * f2i[m2] + f1i[m1] * f2r[m2]);
                }
            }
        }
        constexpr int CI0 = NK;  // imag col base
        *(short*)(fragT + ((k * 512 + ij2) ^ ((k & 7) << 4)))                     = f2bf(fr);
        *(short*)(fragT + (((CI0 + k) * 512 + ij2) ^ (((CI0 + k) & 7) << 4)))     = f2bf(fi);
    }
}

// ---------------- phase 2: MFMA consume one triple ----------------
template <int L>
__device__ __forceinline__ void do_mfma(const char* __restrict__ fragT,
                                        const float* __restrict__ wl,
                                        const int colbase, const int wave,
                                        const int lane, f32x4* __restrict__ P)
{
    constexpr int NK = 2 * L + 1;
    constexpr int NTILES = (2 * NK + 15) / 16;
    const int t = lane & 15, g = lane >> 4;
    const int C = NUMCOLS_[L];
#pragma unroll
    for (int ks = 0; ks < 2; ++ks) {
        const int cb = colbase + wave * 64 + ks * 32 + g * 8;
        const float4* wp = (const float4*)(wl + (size_t)(t * C + cb) * 2);
        const float4 w0 = wp[0], w1 = wp[1], w2 = wp[2], w3 = wp[3];
        bf16x8 aR, aI;
        aR[0] = f2bf(w0.x); aI[0] = f2bf(w0.y); aR[1] = f2bf(w0.z); aI[1] = f2bf(w0.w);
        aR[2] = f2bf(w1.x); aI[2] = f2bf(w1.y); aR[3] = f2bf(w1.z); aI[3] = f2bf(w1.w);
        aR[4] = f2bf(w2.x); aI[4] = f2bf(w2.y); aR[5] = f2bf(w2.z); aI[5] = f2bf(w2.w);
        aR[6] = f2bf(w3.x); aI[6] = f2bf(w3.y); aR[7] = f2bf(w3.z); aI[7] = f2bf(w3.w);
#pragma unroll
        for (int nt = 0; nt < NTILES; ++nt) {
            const int col = nt * 16 + t;
            const int byt = (col * 512 + wave * 128 + ks * 64 + g * 16) ^ ((col & 7) << 4);
            const bf16x8 bfr = *(const bf16x8*)(fragT + byt);
            P[nt]          = __builtin_amdgcn_mfma_f32_16x16x32_bf16(aR, bfr, P[nt], 0, 0, 0);
            P[NTILES + nt] = __builtin_amdgcn_mfma_f32_16x16x32_bf16(aI, bfr, P[NTILES + nt], 0, 0, 0);
        }
    }
}

// ---------------- step driver (double-buffered, 1 barrier/triple) ----------------
template <int L, int IDX>
__device__ __forceinline__ void step(const float* sh_f, char* buf0, char* buf1,
                                     const float* wl, const int tid,
                                     const int wave, const int lane, f32x4* P)
{
    constexpr int NT = TRI_N[L];
    if constexpr (IDX > 0)
        do_mfma<L>(((IDX - 1) & 1) ? buf1 : buf0, wl, (IDX - 1) * 256, wave, lane, P);
    if constexpr (IDX < NT)
        do_phase1<L, TRI_L1[L][IDX], TRI_L2[L][IDX]>(sh_f, (IDX & 1) ? buf1 : buf0, tid);
    __syncthreads();
}

template <int L, int... Is>
__device__ __forceinline__ void run_steps(std::integer_sequence<int, Is...>,
    const float* sh_f, char* buf0, char* buf1, const float* wl,
    int tid, int wave, int lane, f32x4* P)
{
    (step<L, Is>(sh_f, buf0, buf1, wl, tid, wave, lane, P), ...);
}

template <int L>
__device__ void run_l(const float* const* fs, const float* __restrict__ wl,
                      float* __restrict__ out, float* sh_f, char* buf0, char* buf1)
{
    const int b = blockIdx.x, tid = threadIdx.x;
    const int wave = tid >> 6, lane = tid & 63;

    // stage all f_l[b] into LDS (1152 floats)
#pragma unroll
    for (int l = 0; l < 6; ++l) {
        const int cnt = 32 * (2 * l + 1);
        const float* src = fs[l] + (size_t)b * cnt;
        for (int idx = tid; idx < cnt; idx += 256) sh_f[FOFF_[l] + idx] = src[idx];
    }
    __syncthreads();

    constexpr int NK = 2 * L + 1;
    constexpr int NTILES = (2 * NK + 15) / 16;
    f32x4 P[2 * NTILES];
#pragma unroll
    for (int i = 0; i < 2 * NTILES; ++i) P[i] = f32x4{0.f, 0.f, 0.f, 0.f};

    run_steps<L>(std::make_integer_sequence<int, TRI_N[L] + 1>{},
                 sh_f, buf0, buf1, wl, tid, wave, lane, P);

    // ---- epilogue: P partials -> LDS, cross-wave sum + complex combine ----
    float* pb = (float*)buf0;
    {
        const int cn = lane & 15, g = lane >> 4;
#pragma unroll
        for (int m = 0; m < 2; ++m)
#pragma unroll
            for (int nt = 0; nt < NTILES; ++nt)
#pragma unroll
                for (int r = 0; r < 4; ++r)
                    pb[((wave * 2 + m) * NTILES + nt) * 256 + (g * 4 + r) * 16 + cn] =
                        P[m * NTILES + nt][r];
    }
    __syncthreads();

    if (tid < 16 * NK) {
        const int t = tid & 15, k = tid >> 4;
        float oR = 0.f, oI = 0.f;
#pragma unroll
        for (int w = 0; w < 4; ++w) {
            const float* pw = pb + w * 2 * NTILES * 256;
            auto rd = [&](int m, int c) {
                return pw[(m * NTILES + (c >> 4)) * 256 + t * 16 + (c & 15)];
            };
            oR += rd(0, k) - rd(1, NK + k);
            oI += rd(0, NK + k) + rd(1, k);
        }
        float* op = out + OUTOFF_[L] + ((size_t)(b * 16 + t) * NK + k) * 2;
        op[0] = oR;
        op[1] = oI;
    }
}

__global__ __launch_bounds__(256)
void update_kernel(const float* __restrict__ f0, const float* __restrict__ f1,
                   const float* __restrict__ f2, const float* __restrict__ f3,
                   const float* __restrict__ f4, const float* __restrict__ f5,
                   const float* __restrict__ w0, const float* __restrict__ w1,
                   const float* __restrict__ w2, const float* __restrict__ w3,
                   const float* __restrict__ w4, const float* __restrict__ w5,
                   float* __restrict__ out)
{
    __shared__ float sh_f[1152];
    __shared__ __align__(16) char buf0[16384];
    __shared__ __align__(16) char buf1[16384];
    const float* fs[6] = {f0, f1, f2, f3, f4, f5};
    switch (blockIdx.y) {
        case 0: run_l<0>(fs, w0, out, sh_f, buf0, buf1); break;
        case 1: run_l<1>(fs, w1, out, sh_f, buf0, buf1); break;
        case 2: run_l<2>(fs, w2, out, sh_f, buf0, buf1); break;
        case 3: run_l<3>(fs, w3, out, sh_f, buf0, buf1); break;
        case 4: run_l<4>(fs, w4, out, sh_f, buf0, buf1); break;
        default: run_l<5>(fs, w5, out, sh_f, buf0, buf1); break;
    }
}

// ============================================================================
extern "C" void kernel_launch(void* const* d_in, const int* in_sizes, int n_in,
                              void* d_out, int out_size, void* d_ws, size_t ws_size,
                              hipStream_t stream)
{
    const float* f[6];
    const float* w[6];
    for (int l = 0; l < 6; ++l) {
        f[l] = (const float*)d_in[2 * l];      // f0,w0,f1,w1,... dict order
        w[l] = (const float*)d_in[2 * l + 1];
    }
    update_kernel<<<dim3(256, 6), dim3(256), 0, stream>>>(
        f[0], f[1], f[2], f[3], f[4], f[5],
        w[0], w[1], w[2], w[3], w[4], w[5],
        (float*)d_out);
}

// Round 6
// 120.814 us; speedup vs baseline: 4.4462x; 1.2353x over previous
//
#include <hip/hip_runtime.h>
#include <hip/hip_bf16.h>
#include <utility>

// ============================================================================
// CG tensor product + complex weight contraction, fused per batch element.
// LMAX=5, TAU_PRE=16, TAU=16, B=256.
// Inputs (dict order): f0,w0,...,f5,w5. f_l:[256,16,2l+1,2] f32; w_l:[16,C_l,2] f32
// Output: concat of out_l [256,16,2l+1,2] f32 (294912 elems).
//
// Block=(b,L), 256 thr (4 waves). Complex-interleaved-K GEMM scheme:
//  phase1 (VALU): thread ij computes frag[k] complex (CG contract, compile-time
//    coeffs), packs (fR,fI) into one u32, writes LDS row k at byte
//    (k*1024 + ij*4) ^ ((k&7)<<4).   K dim = 512 c' = (ij,R/I interleaved).
//  phase2 (MFMA): P_R[t,k] += A'(wR,-wI)·F,  P_I[t,k] += A''(wI,wR)·F
//    per triple, K split 128 c' per wave, accumulated in P_R/P_I across triples.
//  epilogue: 4-wave partials via LDS, store.
// w pre-converted to bf16 in d_ws by wconv_kernel (per launch).
// ============================================================================

using f32x4  = __attribute__((ext_vector_type(4))) float;
using bf16x8 = __attribute__((ext_vector_type(8))) short;

constexpr int OUTOFF_[6]  = {0, 8192, 32768, 73728, 131072, 204800};
constexpr int NUMCOLS_[6] = {1536, 2560, 3328, 3584, 3584, 3072};
constexpr int FOFF_[6]    = {0, 32, 128, 288, 512, 800};
// bf16-element offsets of w_l inside d_ws (16*C_l*2 elements each)
constexpr int WOFF_[6]    = {0, 49152, 131072, 237568, 352256, 466944};

constexpr int TRI_N[6] = {6, 10, 13, 14, 14, 12};
constexpr int TRI_L1[6][14] = {
    {0,1,2,3,4,5, 0,0,0,0,0,0,0,0},
    {1,1,2,2,3,3,4,4,5,5, 0,0,0,0},
    {1,2,2,2,3,3,3,4,4,4,5,5,5, 0},
    {2,2,3,3,3,3,4,4,4,4,5,5,5,5},
    {2,3,3,3,4,4,4,4,4,5,5,5,5,5},
    {3,3,4,4,4,4,5,5,5,5,5,5, 0,0}};
constexpr int TRI_L2[6][14] = {
    {0,1,2,3,4,5, 0,0,0,0,0,0,0,0},
    {0,1,1,2,2,3,3,4,4,5, 0,0,0,0},
    {1,0,1,2,1,2,3,2,3,4,3,4,5, 0},
    {1,2,0,1,2,3,1,2,3,4,2,3,4,5},
    {2,1,2,3,0,1,2,3,4,1,2,3,4,5},
    {2,3,1,2,3,4,0,1,2,3,4,5, 0,0}};

// ---------------- compile-time Clebsch-Gordan ----------------
constexpr double cfact(int n) { double r = 1.0; for (int i = 2; i <= n; ++i) r *= (double)i; return r; }

constexpr double csqrt(double x) {
    if (x <= 0.0) return 0.0;
    double g = x < 1.0 ? 1.0 : x;
    for (int i = 0; i < 200; ++i) {
        double n = 0.5 * (g + x / g);
        if (n == g) break;
        g = n;
    }
    return g;
}

constexpr double cg_c(int l1, int l2, int l, int m1, int m2, int m) {
    double pref = (2.0 * l + 1.0) * cfact(l + l1 - l2) * cfact(l - l1 + l2) *
                  cfact(l1 + l2 - l) / cfact(l1 + l2 + l + 1);
    pref *= cfact(l + m) * cfact(l - m) * cfact(l1 - m1) * cfact(l1 + m1) *
            cfact(l2 - m2) * cfact(l2 + m2);
    pref = csqrt(pref);
    int kmin = 0;
    if (l2 - l - m1 > kmin) kmin = l2 - l - m1;
    if (l1 + m2 - l > kmin) kmin = l1 + m2 - l;
    int kmax = l1 + l2 - l;
    if (l1 - m1 < kmax) kmax = l1 - m1;
    if (l2 + m2 < kmax) kmax = l2 + m2;
    double s = 0.0;
    for (int k = kmin; k <= kmax; ++k) {
        double d = cfact(k) * cfact(l1 + l2 - l - k) * cfact(l1 - m1 - k) *
                   cfact(l2 + m2 - k) * cfact(l - l2 + m1 + k) * cfact(l - l1 - m2 + k);
        s += ((k & 1) ? -1.0 : 1.0) / d;
    }
    return pref * s;
}

template <int L1, int L2, int L>
struct CGTab {
    static constexpr int N1 = 2 * L1 + 1, N2 = 2 * L2 + 1;
    struct T { float v[N1 * N2]; };
    static constexpr T build() {
        T t{};
        for (int m1 = -L1; m1 <= L1; ++m1)
            for (int m2 = -L2; m2 <= L2; ++m2) {
                int m = m1 + m2;
                double v = 0.0;
                if (m >= -L && m <= L) v = cg_c(L1, L2, L, m1, m2, m);
                t.v[(m1 + L1) * N2 + (m2 + L2)] = (float)v;
            }
        return t;
    }
    static constexpr T TAB = build();
};

// ---------------- helpers ----------------
__device__ __forceinline__ unsigned short f2bf(float f) {
    __hip_bfloat16 h = __float2bfloat16(f);
    return *reinterpret_cast<unsigned short*>(&h);
}

// ---------------- w -> bf16 pre-convert ----------------
__global__ __launch_bounds__(256)
void wconv_kernel(const float* __restrict__ w0, const float* __restrict__ w1,
                  const float* __restrict__ w2, const float* __restrict__ w3,
                  const float* __restrict__ w4, const float* __restrict__ w5,
                  unsigned short* __restrict__ dst)
{
    const int l = blockIdx.y;
    const float* srcs[6] = {w0, w1, w2, w3, w4, w5};
    const float* src = srcs[l];
    const int cnt = 16 * NUMCOLS_[l] * 2;
    const int i4 = (blockIdx.x * 256 + threadIdx.x) * 4;
    if (i4 < cnt) {
        const float4 v = *(const float4*)(src + i4);
        ushort4 o;
        o.x = f2bf(v.x); o.y = f2bf(v.y); o.z = f2bf(v.z); o.w = f2bf(v.w);
        *(ushort4*)(dst + WOFF_[l] + i4) = o;
    }
}

// ---------------- phase 1: CG contract -> packed complex LDS rows ----------------
template <int L, int L1, int L2>
__device__ __forceinline__ void do_phase1(const float* __restrict__ sh_f,
                                          char* __restrict__ frag, const int tid)
{
    constexpr int N1 = 2 * L1 + 1, N2 = 2 * L2 + 1, NK = 2 * L + 1, SH = L1 + L2 - L;
    const int i = tid >> 4, j = tid & 15;
    const float* f1 = sh_f + FOFF_[L1] + i * (2 * N1);
    const float* f2 = sh_f + FOFF_[L2] + j * (2 * N2);
    float f1r[N1], f1i[N1], f2r[N2], f2i[N2];
#pragma unroll
    for (int m = 0; m < N1; ++m) { float2 v = *(const float2*)(f1 + 2 * m); f1r[m] = v.x; f1i[m] = v.y; }
#pragma unroll
    for (int n = 0; n < N2; ++n) { float2 v = *(const float2*)(f2 + 2 * n); f2r[n] = v.x; f2i[n] = v.y; }

    const int ij4 = tid * 4;
#pragma unroll
    for (int k = 0; k < NK; ++k) {
        const int kk = k + SH;
        float fr = 0.f, fi = 0.f;
#pragma unroll
        for (int m1 = 0; m1 < N1; ++m1) {
            const int m2 = kk - m1;
            if (m2 >= 0 && m2 < N2) {  // compile-time after unroll
                const float c = CGTab<L1, L2, L>::TAB.v[m1 * N2 + m2];
                if (c != 0.f) {        // folded constant -> zero terms DCE'd
                    fr += c * (f1r[m1] * f2r[m2] - f1i[m1] * f2i[m2]);
                    fi += c * (f1r[m1] * f2i[m2] + f1i[m1] * f2r[m2]);
                }
            }
        }
        const unsigned u = ((unsigned)f2bf(fi) << 16) | (unsigned)f2bf(fr);
        *(unsigned*)(frag + ((k * 1024 + ij4) ^ ((k & 7) << 4))) = u;
    }
}

// ---------------- phase 2: MFMA consume one triple ----------------
template <int L>
__device__ __forceinline__ void do_mfma(const char* __restrict__ frag,
                                        const unsigned short* __restrict__ wbf,
                                        const int cbase, const int wave,
                                        const int lane, f32x4& PR, f32x4& PI)
{
    constexpr int NK = 2 * L + 1;
    const int t = lane & 15, g = lane >> 4;
    int nc = lane & 15; if (nc > NK - 1) nc = NK - 1;   // clamped B col (dup, never read)
    const int C = NUMCOLS_[L];
#pragma unroll
    for (int ks = 0; ks < 4; ++ks) {
        const int c0 = wave * 64 + ks * 16 + 4 * g;     // complex col window (4 cols)
        // A: 4 complex w values = 8 bf16 = 16B
        uint4 wa = *(const uint4*)(wbf + (size_t)(t * C + cbase + c0) * 2);
        uint4 a1, a2;                                    // A' = (wR,-wI), A'' = (wI,wR)
        a1.x = wa.x ^ 0x80000000u; a1.y = wa.y ^ 0x80000000u;
        a1.z = wa.z ^ 0x80000000u; a1.w = wa.w ^ 0x80000000u;
        a2.x = (wa.x >> 16) | (wa.x << 16); a2.y = (wa.y >> 16) | (wa.y << 16);
        a2.z = (wa.z >> 16) | (wa.z << 16); a2.w = (wa.w >> 16) | (wa.w << 16);
        // B: 16B of interleaved (fR,fI) along ij for col nc
        const int byt = (nc * 1024 + c0 * 4) ^ ((nc & 7) << 4);
        const bf16x8 B = *(const bf16x8*)(frag + byt);
        PR = __builtin_amdgcn_mfma_f32_16x16x32_bf16(*(const bf16x8*)&a1, B, PR, 0, 0, 0);
        PI = __builtin_amdgcn_mfma_f32_16x16x32_bf16(*(const bf16x8*)&a2, B, PI, 0, 0, 0);
    }
}

// ---------------- step driver (double-buffered, 1 barrier/triple) ----------------
template <int L, int IDX>
__device__ __forceinline__ void step(const float* sh_f, char* buf0, char* buf1,
                                     const unsigned short* wbf, const int tid,
                                     const int wave, const int lane,
                                     f32x4& PR, f32x4& PI)
{
    constexpr int NT = TRI_N[L];
    if constexpr (IDX > 0)
        do_mfma<L>(((IDX - 1) & 1) ? buf1 : buf0, wbf, (IDX - 1) * 256, wave, lane, PR, PI);
    if constexpr (IDX < NT)
        do_phase1<L, TRI_L1[L][IDX], TRI_L2[L][IDX]>(sh_f, (IDX & 1) ? buf1 : buf0, tid);
    __syncthreads();
}

template <int L, int... Is>
__device__ __forceinline__ void run_steps(std::integer_sequence<int, Is...>,
    const float* sh_f, char* buf0, char* buf1, const unsigned short* wbf,
    int tid, int wave, int lane, f32x4& PR, f32x4& PI)
{
    (step<L, Is>(sh_f, buf0, buf1, wbf, tid, wave, lane, PR, PI), ...);
}

template <int L>
__device__ void run_l(const float* const* fs, const unsigned short* __restrict__ wbf,
                      float* __restrict__ out, float* sh_f, char* buf0, char* buf1)
{
    const int b = blockIdx.x, tid = threadIdx.x;
    const int wave = tid >> 6, lane = tid & 63;

    // stage all f_l[b] into LDS (1152 floats) via float4.
    // f_l per-b size = 32*(2l+1) floats = 8*(2l+1) float4  (BUGFIX of round 5:
    // was 16*(2l+1) float4 -> 2x stride + LDS segment overflow).
#pragma unroll
    for (int l = 0; l < 6; ++l) {
        const int cnt4 = 8 * (2 * l + 1);
        const float4* s4 = (const float4*)(fs[l] + (size_t)b * 32 * (2 * l + 1));
        float4* d4 = (float4*)(sh_f + FOFF_[l]);
        for (int idx = tid; idx < cnt4; idx += 256) d4[idx] = s4[idx];
    }
    __syncthreads();

    f32x4 PR = {0.f, 0.f, 0.f, 0.f}, PI = {0.f, 0.f, 0.f, 0.f};

    run_steps<L>(std::make_integer_sequence<int, TRI_N[L] + 1>{},
                 sh_f, buf0, buf1, wbf, tid, wave, lane, PR, PI);

    // ---- epilogue: 4-wave partial sums via LDS ----
    constexpr int NK = 2 * L + 1;
    float* pb = (float*)buf0;   // 4 waves * 2 * 256 f32 = 8KB <= buf size
    {
        const int kcol = lane & 15, g = lane >> 4;   // D: col=lane&15 (k), row=4g+r (t)
#pragma unroll
        for (int r = 0; r < 4; ++r) {
            pb[(wave * 2 + 0) * 256 + (4 * g + r) * 16 + kcol] = PR[r];
            pb[(wave * 2 + 1) * 256 + (4 * g + r) * 16 + kcol] = PI[r];
        }
    }
    __syncthreads();

    if (tid < 16 * NK) {
        const int t = tid & 15, k = tid >> 4;
        float oR = 0.f, oI = 0.f;
#pragma unroll
        for (int w = 0; w < 4; ++w) {
            oR += pb[(w * 2 + 0) * 256 + t * 16 + k];
            oI += pb[(w * 2 + 1) * 256 + t * 16 + k];
        }
        float* op = out + OUTOFF_[L] + ((size_t)(b * 16 + t) * NK + k) * 2;
        op[0] = oR;
        op[1] = oI;
    }
}

__global__ __launch_bounds__(256, 5)
void update_kernel(const float* __restrict__ f0, const float* __restrict__ f1,
                   const float* __restrict__ f2, const float* __restrict__ f3,
                   const float* __restrict__ f4, const float* __restrict__ f5,
                   const unsigned short* __restrict__ wbf,
                   float* __restrict__ out)
{
    __shared__ float sh_f[1152];
    __shared__ __align__(16) char buf0[11264];   // 11 rows x 1KB
    __shared__ __align__(16) char buf1[11264];
    const float* fs[6] = {f0, f1, f2, f3, f4, f5};
    // Heavy-L-first dispatch: y=0 (dispatched first) -> L=5, ... y=5 -> L=0
    switch (blockIdx.y) {
        case 0: run_l<5>(fs, wbf + WOFF_[5], out, sh_f, buf0, buf1); break;
        case 1: run_l<4>(fs, wbf + WOFF_[4], out, sh_f, buf0, buf1); break;
        case 2: run_l<3>(fs, wbf + WOFF_[3], out, sh_f, buf0, buf1); break;
        case 3: run_l<2>(fs, wbf + WOFF_[2], out, sh_f, buf0, buf1); break;
        case 4: run_l<1>(fs, wbf + WOFF_[1], out, sh_f, buf0, buf1); break;
        default: run_l<0>(fs, wbf + WOFF_[0], out, sh_f, buf0, buf1); break;
    }
}

// ============================================================================
extern "C" void kernel_launch(void* const* d_in, const int* in_sizes, int n_in,
                              void* d_out, int out_size, void* d_ws, size_t ws_size,
                              hipStream_t stream)
{
    const float* f[6];
    const float* w[6];
    for (int l = 0; l < 6; ++l) {
        f[l] = (const float*)d_in[2 * l];      // f0,w0,f1,w1,... dict order
        w[l] = (const float*)d_in[2 * l + 1];
    }
    unsigned short* wbf = (unsigned short*)d_ws;  // 565248 bf16 = 1.13 MB

    // convert w to bf16 (max segment 114688 f32 -> 112 blocks of 256x4)
    wconv_kernel<<<dim3(112, 6), dim3(256), 0, stream>>>(
        w[0], w[1], w[2], w[3], w[4], w[5], wbf);

    update_kernel<<<dim3(256, 6), dim3(256), 0, stream>>>(
        f[0], f[1], f[2], f[3], f[4], f[5], wbf, (float*)d_out);
}